// Round 13
// baseline (79.772 us; speedup 1.0000x reference)
//
#include <hip/hip_runtime.h>
#include <math.h>

// NGRU via MFMA, R13 = R9 math + two anti-phased 32-row groups per block.
// Only layer 1 of the 2 parallel GRU layers contributes (reference returns
// h_final[-1]); layer 0 is skipped.
//
// Shapes: x (64,48,256,64) f32; Wih/Whh (2,192,64); bih/bhh (2,192).
// rows = B*N = 16384 independent GRU sequences, T=48, H=64.
//
// R12 lesson: more waves in the SAME barrier phase = neutral; all pipes
// (MFMA, VALU/TRANS, LDS) burst sequentially because every wave is at the
// same phase. Rows are independent -> split each block's 64 rows into two
// 32-row groups scheduled HALF A STEP apart:
//   R1: g0 {ds_read+MFMA(t)}      || g1 {epilogue(t)+h/x-stage}   ; barrier
//   R2: g0 {epilogue(t)+stage}    || g1 {ds_read+MFMA(t+1)}       ; barrier
// Waves 0-3 = g0, 4-7 = g1 -> each SIMD hosts one wave of each group:
// matrix pipe and VALU/TRANS pipe overlap BY CONSTRUCTION. Barriers only
// protect each group's own write->read edge (groups share no data).
// s_setprio(1) around MFMA is now in its proven regime (role diversity).
//
// Per-wave work identical to R9: j-slice 16 cols x 32 rows, all 4 gates,
// 8 ds_read_b128 + 24 fp16 MFMA + 8-row epilogue. Chain order, pkh2
// conversions, gate math all R9-exact -> bit-identical numerics.
// x loads issued one region before staging (~600 cyc cover; x is
// L3-resident after iteration 1).
// waves_per_eu(2,2): 256-VGPR budget at the 1-block/CU residency.

#define TT 48
#define HH 64
#define GG 192
#define NN 256
#define RPB 64          // rows per block: two 32-row groups
#define NTHREADS 512    // 8 waves: 0-3 group0, 4-7 group1
#define AK 136          // A row stride in halfs (128 + 8 pad)
#define HBUF (RPB*AK)   // halfs per A buffer (8704)

typedef _Float16 h8 __attribute__((ext_vector_type(8)));   // 8 fp16 (4 VGPRs)
typedef __attribute__((ext_vector_type(4))) float f32x4;   // MFMA accum
typedef __attribute__((ext_vector_type(4))) unsigned u32x4;

__device__ __forceinline__ float sigm(float v) {
    return __builtin_amdgcn_rcpf(1.f + __expf(-v));
}
__device__ __forceinline__ float tanh_f(float v) {
    float a = fabsf(v);
    float e = __expf(2.f * a);
    float t = 1.f - 2.f * __builtin_amdgcn_rcpf(e + 1.f);
    return v < 0.f ? -t : t;
}
// pack 2 f32 -> dword of 2 fp16 (RNE)
__device__ __forceinline__ unsigned pkh2(float a, float b) {
    union { _Float16 h[2]; unsigned u; } c;
    c.h[0] = (_Float16)a; c.h[1] = (_Float16)b;
    return c.u;
}

#define MF(A, B, C) __builtin_amdgcn_mfma_f32_16x16x32_f16(A, B, C, 0, 0, 0)

__global__ __launch_bounds__(NTHREADS)
__attribute__((amdgpu_waves_per_eu(2, 2)))
void ngru_mfma13(const float* __restrict__ x,
                 const float* __restrict__ Wih,
                 const float* __restrict__ Whh,
                 const float* __restrict__ bih,
                 const float* __restrict__ bhh,
                 float* __restrict__ out)
{
    extern __shared__ __align__(16) _Float16 lds_h[];  // 2 x HBUF halfs

    const int tid  = threadIdx.x;
    const int lane = tid & 63;
    const int wv   = tid >> 6;          // wave 0..7
    const int grp  = wv >> 2;           // 0 = group0, 1 = group1
    const int nw   = wv & 3;            // j slice [16nw, 16nw+16)
    const int c0   = lane & 15;
    const int rq   = lane >> 4;
    const int j    = nw * 16 + c0;
    const int rbase = grp * 32;         // group's row range in A buffers

    const int grow0 = blockIdx.x * RPB;
    const int bb    = grow0 / NN;       // 64-row blocks never straddle a batch
    const int n0    = grow0 % NN;

    const float* Wi = Wih + GG * HH;    // layer 1
    const float* Wh = Whh + GG * HH;

    // ---- B fragments (fp16) in registers: 12 kt-slots (R9 layout) ----
    // slot: r -> 0..3 (kt0,1 = Wi; kt2,3 = Wh); z -> 4..7;
    //       gin -> 8,9 (Wi, A kt0,1); ghn -> 10,11 (Wh, A kt2,3).
    h8 Bf[12];
    #pragma unroll
    for (int g = 0; g < 4; ++g) {
        const int ktlo = (g == 3) ? 2 : 0;
        const int kthi = (g == 2) ? 2 : 4;
        #pragma unroll
        for (int kt = ktlo; kt < kthi; ++kt) {
            const int slot = (g < 2) ? g * 4 + kt : 8 + (g - 2) * 2 + (kt & 1);
            const bool isWi = (kt < 2);
            const int gbase = (g >= 2) ? 2 : g;
            const float* src = (isWi ? Wi : Wh)
                             + (gbase * 64 + j) * HH + (kt & 1) * 32 + rq * 8;
            h8 f;
            #pragma unroll
            for (int q = 0; q < 8; ++q) f[q] = (_Float16)src[q];
            Bf[slot] = f;
        }
    }

    // ---- biases (layer 1), r/z pre-summed; n biases separate ----
    const float brz  = bih[GG + j]      + bhh[GG + j];
    const float bzz  = bih[GG + 64 + j] + bhh[GG + 64 + j];
    const float bin_ = bih[GG + 128 + j];
    const float bhn_ = bhh[GG + 128 + j];

    // ---- init buf0: zero h region (all 64 rows), stage x_0 ----
    {
        const int zr = tid >> 3;          // 0..63
        const int zc = (tid & 7) * 8;     // 0..56
        *(u32x4*)(lds_h + zr * AK + 64 + zc) = (u32x4){0u, 0u, 0u, 0u};
        const float* xsrc = x + ((size_t)(bb * TT) * NN + n0 + zr) * HH + zc;
        float4 a = *(const float4*)xsrc;
        float4 b = *(const float4*)(xsrc + 4);
        *(u32x4*)(lds_h + zr * AK + zc) =
            (u32x4){pkh2(a.x, a.y), pkh2(a.z, a.w), pkh2(b.x, b.y), pkh2(b.z, b.w)};
    }

    // staging geometry (per group: 256 threads cover 32 rows x 64 halfs)
    const int gt   = tid & 255;
    const int srow = rbase + (gt >> 3);   // row within block's 64
    const int skc  = (gt & 7) * 8;

    float hreg[2][4];
    #pragma unroll
    for (int m = 0; m < 2; ++m)
        #pragma unroll
        for (int r = 0; r < 4; ++r) hreg[m][r] = 0.f;

    // accumulators (named, persist across regions)
    f32x4 a00, a01, a02, a03, a10, a11, a12, a13;
    float4 pa, pb;                        // in-flight x loads

    // R9-exact MFMA cluster: bias-init accs + chains, reads BUF group rows
#define MFMA_BLOCK(BUF)                                                        \
    {                                                                          \
        const _Float16* ab0 = (BUF) + (rbase + c0) * AK + rq * 8;              \
        const _Float16* ab1 = ab0 + 16 * AK;                                   \
        h8 A0 = *(const h8*)(ab0);                                             \
        h8 A1 = *(const h8*)(ab0 + 32);                                        \
        h8 A2 = *(const h8*)(ab0 + 64);                                        \
        h8 A3 = *(const h8*)(ab0 + 96);                                        \
        h8 C0 = *(const h8*)(ab1);                                             \
        h8 C1 = *(const h8*)(ab1 + 32);                                        \
        h8 C2 = *(const h8*)(ab1 + 64);                                        \
        h8 C3 = *(const h8*)(ab1 + 96);                                        \
        a00 = (f32x4){brz,  brz,  brz,  brz };                                 \
        a01 = (f32x4){bzz,  bzz,  bzz,  bzz };                                 \
        a02 = (f32x4){bin_, bin_, bin_, bin_};                                 \
        a03 = (f32x4){bhn_, bhn_, bhn_, bhn_};                                 \
        a10 = a00; a11 = a01; a12 = a02; a13 = a03;                            \
        __builtin_amdgcn_s_setprio(1);                                         \
        a00 = MF(A0, Bf[0], a00);  a00 = MF(A1, Bf[1], a00);                   \
        a00 = MF(A2, Bf[2], a00);  a00 = MF(A3, Bf[3], a00);                   \
        a01 = MF(A0, Bf[4], a01);  a01 = MF(A1, Bf[5], a01);                   \
        a01 = MF(A2, Bf[6], a01);  a01 = MF(A3, Bf[7], a01);                   \
        a02 = MF(A0, Bf[8], a02);  a02 = MF(A1, Bf[9], a02);                   \
        a03 = MF(A2, Bf[10], a03); a03 = MF(A3, Bf[11], a03);                  \
        a10 = MF(C0, Bf[0], a10);  a10 = MF(C1, Bf[1], a10);                   \
        a10 = MF(C2, Bf[2], a10);  a10 = MF(C3, Bf[3], a10);                   \
        a11 = MF(C0, Bf[4], a11);  a11 = MF(C1, Bf[5], a11);                   \
        a11 = MF(C2, Bf[6], a11);  a11 = MF(C3, Bf[7], a11);                   \
        a12 = MF(C0, Bf[8], a12);  a12 = MF(C1, Bf[9], a12);                   \
        a13 = MF(C2, Bf[10], a13); a13 = MF(C3, Bf[11], a13);                  \
        __builtin_amdgcn_s_setprio(0);                                         \
    }

#define EPI_M(AM0, AM1, AM2, AM3, M, NXT, WR)                                  \
    _Pragma("unroll") for (int r = 0; r < 4; ++r) {                            \
        const int row = rbase + (M) * 16 + rq * 4 + r;                         \
        float rg = sigm(AM0[r]);                                               \
        float zg = sigm(AM1[r]);                                               \
        float ng = tanh_f(fmaf(rg, AM3[r], AM2[r]));                           \
        float hn = fmaf(zg, hreg[M][r] - ng, ng);                              \
        hreg[M][r] = hn;                                                       \
        if (WR) (NXT)[row * AK + 64 + j] = (_Float16)hn;                       \
    }

#define LOAD_X(T1)                                                             \
    {                                                                          \
        const float* xs =                                                      \
            x + ((size_t)(bb * TT + (T1)) * NN + n0 + srow) * HH + skc;        \
        pa = *(const float4*)xs;                                               \
        pb = *(const float4*)(xs + 4);                                         \
    }

#define STAGE_X(NXT)                                                           \
    *(u32x4*)((NXT) + srow * AK + skc) =                                       \
        (u32x4){pkh2(pa.x, pa.y), pkh2(pa.z, pa.w),                            \
                pkh2(pb.x, pb.y), pkh2(pb.z, pb.w)};

    __syncthreads();   // buf0 (h zeros + x0) ready

    // prologue: group1 runs half a step ahead — MFMA(0) now
    if (grp) {
        if (TT > 1) LOAD_X(1);
        MFMA_BLOCK(lds_h);
    }

    for (int t = 0; t < TT; ++t) {
        _Float16* cur = lds_h + (t & 1) * HBUF;
        _Float16* nxt = lds_h + ((t & 1) ^ 1) * HBUF;
        const bool hasNext = (t + 1 < TT);

        // ---- Region 1: g0 MFMA(t)  ||  g1 epilogue(t)+stage ----
        if (!grp) {
            if (hasNext) LOAD_X(t + 1);
            MFMA_BLOCK(cur);
        } else {
            EPI_M(a00, a01, a02, a03, 0, nxt, hasNext);
            EPI_M(a10, a11, a12, a13, 1, nxt, hasNext);
            if (hasNext) STAGE_X(nxt);
        }
        __syncthreads();   // B1: g1's writes -> g1's reads below

        // ---- Region 2: g0 epilogue(t)+stage  ||  g1 MFMA(t+1) ----
        if (!grp) {
            EPI_M(a00, a01, a02, a03, 0, nxt, hasNext);
            EPI_M(a10, a11, a12, a13, 1, nxt, hasNext);
            if (hasNext) STAGE_X(nxt);
        } else if (hasNext) {
            if (t + 2 < TT) LOAD_X(t + 2);
            MFMA_BLOCK(nxt);
        }
        __syncthreads();   // B2: g0's writes -> g0's reads next iter
    }

#undef MFMA_BLOCK
#undef EPI_M
#undef LOAD_X
#undef STAGE_X

    #pragma unroll
    for (int m = 0; m < 2; ++m)
        #pragma unroll
        for (int r = 0; r < 4; ++r)
            out[(size_t)(grow0 + rbase + m * 16 + rq * 4 + r) * HH + j] =
                hreg[m][r];
}

extern "C" void kernel_launch(void* const* d_in, const int* in_sizes, int n_in,
                              void* d_out, int out_size, void* d_ws, size_t ws_size,
                              hipStream_t stream) {
    const float* x   = (const float*)d_in[0];
    const float* Wih = (const float*)d_in[1];
    const float* Whh = (const float*)d_in[2];
    const float* bih = (const float*)d_in[3];
    const float* bhh = (const float*)d_in[4];
    float* out = (float*)d_out;

    const int lds_bytes = 2 * HBUF * (int)sizeof(_Float16);   // 34,816 B
    (void)hipFuncSetAttribute((const void*)ngru_mfma13,
                        hipFuncAttributeMaxDynamicSharedMemorySize, lds_bytes);

    dim3 grid(16384 / RPB);     // 256 blocks, 1 per CU
    dim3 block(NTHREADS);
    ngru_mfma13<<<grid, block, lds_bytes, stream>>>(x, Wih, Whh, bih, bhh, out);
}